// Round 8
// baseline (100.953 us; speedup 1.0000x reference)
//
#include <hip/hip_runtime.h>

// SKANLinear: y[b,o] = sum_{i=0}^{IN} weight[o,i] * sin(w[o,i] * x_ext[b,i])
// x_ext[b,IN] = 1.0. B=2048, IN=256, OUT=256. f32.
//
// R12: INSTRUMENTATION ROUND — exact R4 (best: 76.2us) + one asm-opaqued
// duplicate of the core compute. Purpose: double kernel time (~25->~50us)
// so skan_kernel enters the rocprof top-5 window and reports VALUBusy /
// OccupancyPercent for the REAL structure (never yet observed; six
// structural variants all ~2-2.5x over the issue floor and every
// single-cause theory — sin rate (R7), SMEM (R6), LDS pipe (R8),
// occupancy (R11) — is falsified; direct counters required).
// Dummy rep: identical issue profile (2 mul + 2 sin + 2 fma per i), inputs
// made opaque with asm "+v" so CSE can't merge it with the real chain,
// results kept live with an asm sink (never stored). dur_us regression is
// intentional and will be reverted next round.
//
// Decision table: VALUBusy>=85% -> issue-bound, pivot to cycle-count
// reduction; <=60% -> stall-bound, attack the shared serializer.

#define IN_DIM 256
#define OUT_DIM 256
#define LDW 257
#define LXS 65            // LDS x-tile row stride (odd -> bank-friendly)
#define INV_2PI 0.15915494309189535f

__global__ __launch_bounds__(256, 4)
void skan_kernel(const float* __restrict__ x,      // [2048][256]
                 const float* __restrict__ weight, // [256][257]
                 const float* __restrict__ wfreq,  // [256][257]
                 float* __restrict__ y)            // [2048][256]
{
    __shared__ float lx[64 * LXS];   // x[b][i-chunk] * INV_2PI, transposed access

    const int t  = threadIdx.x;
    const int l  = t & 63;                                   // lane = local b
    const int wv = __builtin_amdgcn_readfirstlane(t >> 6);   // wave id, uniform

    const int obase = (blockIdx.x & 31) * 8;
    const int b0    = (blockIdx.x >> 5) * 64;

    const int o0 = obase + wv * 2;
    const int o1 = o0 + 1;
    const float* __restrict__ w0r = wfreq  + o0 * LDW;  // uniform -> s_load
    const float* __restrict__ g0r = weight + o0 * LDW;
    const float* __restrict__ w1r = wfreq  + o1 * LDW;
    const float* __restrict__ g1r = weight + o1 * LDW;

    // staging lane mapping: 16 rows per wave, 4 rows per instr, coalesced
    const int srow = wv * 16 + (l >> 4);   // +4k below
    const int scol = (l & 15) * 4;         // dword col within 64-wide chunk

    // bias column (i=256, x_ext=1)
    float acc0 = g0r[IN_DIM] * __builtin_amdgcn_sinf(w0r[IN_DIM] * INV_2PI);
    float acc1 = g1r[IN_DIM] * __builtin_amdgcn_sinf(w1r[IN_DIM] * INV_2PI);

    // dummy accumulators for the instrumentation rep (never stored)
    float accd0 = 0.0f, accd1 = 0.0f;

    // ---- prologue: stage chunk 0
    {
        const float* gx = x + b0 * IN_DIM;  // ic = 0
#pragma unroll
        for (int k = 0; k < 4; ++k) {
            const int r = srow + 4 * k;
            const float4 v = *(const float4*)(gx + r * IN_DIM + scol);
            float* d = &lx[r * LXS + scol];
            d[0] = v.x * INV_2PI; d[1] = v.y * INV_2PI;
            d[2] = v.z * INV_2PI; d[3] = v.w * INV_2PI;
        }
    }

    for (int ic = 0; ic < 4; ++ic) {
        __syncthreads();

        // copy my b-row's chunk to registers (ds_read, stride-65: 2-way free)
        float xs[64];
#pragma unroll
        for (int j = 0; j < 64; ++j) xs[j] = lx[l * LXS + j];

        __syncthreads();

        // stage next chunk while compute runs (regs double-buffer the tile)
        if (ic < 3) {
            const float* gx = x + b0 * IN_DIM + (ic + 1) * 64;
#pragma unroll
            for (int k = 0; k < 4; ++k) {
                const int r = srow + 4 * k;
                const float4 v = *(const float4*)(gx + r * IN_DIM + scol);
                float* d = &lx[r * LXS + scol];
                d[0] = v.x * INV_2PI; d[1] = v.y * INV_2PI;
                d[2] = v.z * INV_2PI; d[3] = v.w * INV_2PI;
            }
        }

        // ---- real core: identical to R4 ----
        const int ib = ic * 64;
#pragma unroll
        for (int j = 0; j < 64; ++j) {
            const float xv = xs[j];
            acc0 = fmaf(g0r[ib + j], __builtin_amdgcn_sinf(w0r[ib + j] * xv), acc0);
            acc1 = fmaf(g1r[ib + j], __builtin_amdgcn_sinf(w1r[ib + j] * xv), acc1);
        }

        // ---- instrumentation rep: same issue profile, opaque inputs so
        // CSE cannot share the sin/fma chains with the real core ----
#pragma unroll
        for (int j = 0; j < 64; ++j) {
            float xd = xs[j];
            asm volatile("" : "+v"(xd));   // opaque copy: forces fresh sin
            accd0 = fmaf(g0r[ib + j], __builtin_amdgcn_sinf(w0r[ib + j] * xd), accd0);
            accd1 = fmaf(g1r[ib + j], __builtin_amdgcn_sinf(w1r[ib + j] * xd), accd1);
        }
    }

    // store: per-lane (b,o) result. 2 scatter stores per wave (64 rows).
    y[(b0 + l) * OUT_DIM + o0] = acc0;
    y[(b0 + l) * OUT_DIM + o1] = acc1;

    // keep the dummy chains live without ever writing memory (rule #17)
    asm volatile("" :: "v"(accd0), "v"(accd1));
}

extern "C" void kernel_launch(void* const* d_in, const int* in_sizes, int n_in,
                              void* d_out, int out_size, void* d_ws, size_t ws_size,
                              hipStream_t stream) {
    const float* x      = (const float*)d_in[0];
    const float* weight = (const float*)d_in[1];
    const float* wfreq  = (const float*)d_in[2];
    float* y            = (float*)d_out;

    const int B = in_sizes[0] / IN_DIM;            // 2048
    const int grid = (B / 64) * (OUT_DIM / 8);     // 32 * 32 = 1024

    skan_kernel<<<grid, 256, 0, stream>>>(x, weight, wfreq, y);
}